// Round 5
// baseline (69.953 us; speedup 1.0000x reference)
//
#include <hip/hip_runtime.h>
#include <hip/hip_bf16.h>
#include <stdint.h>

#define G1CAST(p) ((const __attribute__((address_space(1))) void*)(p))
#define L3CAST(p) ((__attribute__((address_space(3))) void*)(p))

typedef short bf16x8 __attribute__((ext_vector_type(8)));
typedef float f32x16 __attribute__((ext_vector_type(16)));

static __device__ __forceinline__ short f2bf(float f) {
    __hip_bfloat16 b = __float2bfloat16(f);
    return __builtin_bit_cast(short, b);
}

// ---------------------------------------------------------------------------
// Kernel 1: relayout+convert weights to bf16.
// W_cat[n][gate][j][kk], kk in [0,1024): kk<512 -> W_ih[n][gate*512+j][kk]
//                                        kk>=512 -> W_hh[n][gate*512+j][kk-512]
// ---------------------------------------------------------------------------
__global__ __launch_bounds__(256) void wconv_kernel(const float* __restrict__ Wih,
                                                    const float* __restrict__ Whh,
                                                    short* __restrict__ Wcat) {
    const int tid = blockIdx.x * 256 + threadIdx.x;
    const int64_t e = (int64_t)tid * 8;
    const int kk = (int)(e & 1023);
    const int row = (int)(e >> 10);
    const int n = row / 1536;
    const int gr = row - n * 1536;
    const float* src = (kk < 512)
        ? Wih + ((int64_t)n * 786432 + (int64_t)gr * 512 + kk)
        : Whh + ((int64_t)n * 786432 + (int64_t)gr * 512 + (kk - 512));
    const float4 a = ((const float4*)src)[0];
    const float4 b = ((const float4*)src)[1];
    bf16x8 o;
    o[0] = f2bf(a.x); o[1] = f2bf(a.y); o[2] = f2bf(a.z); o[3] = f2bf(a.w);
    o[4] = f2bf(b.x); o[5] = f2bf(b.y); o[6] = f2bf(b.z); o[7] = f2bf(b.w);
    *(bf16x8*)(Wcat + e) = o;
}

// ---------------------------------------------------------------------------
// Kernel 1b: convert x,h -> bf16 pre-swizzled LDS images (256-row tiles).
// Image tile (bt,nblk,ks) = 16 KB: [r 0..255][chunk c at pos c^((r>>1)&3)][16B]
// ks<16 -> x k-slice ks, ks>=16 -> h k-slice ks-16.
// ---------------------------------------------------------------------------
__global__ __launch_bounds__(256) void aconv_kernel(const float* __restrict__ x,
                                                    const float* __restrict__ h,
                                                    short* __restrict__ Aimg) {
    const int gid = blockIdx.x * 256 + threadIdx.x;   // 1,048,576 threads
    const int c4 = gid & 3;
    const int r = (gid >> 2) & 255;
    const int tile = gid >> 10;                       // 0..1023
    const int ks = tile & 31;
    const int nblk = (tile >> 5) & 7;
    const int bt = tile >> 8;                         // 0..3
    const float* base = (ks < 16) ? x : h;
    const float* src = base + ((size_t)(bt * 256 + r) * 4096
                               + nblk * 512 + (ks & 15) * 32 + c4 * 8);
    const float4 a = ((const float4*)src)[0];
    const float4 b = ((const float4*)src)[1];
    bf16x8 o;
    o[0] = f2bf(a.x); o[1] = f2bf(a.y); o[2] = f2bf(a.z); o[3] = f2bf(a.w);
    o[4] = f2bf(b.x); o[5] = f2bf(b.y); o[6] = f2bf(b.z); o[7] = f2bf(b.w);
    *(bf16x8*)(Aimg + (size_t)tile * 8192 + r * 32 + ((c4 ^ ((r >> 1) & 3)) * 8)) = o;
}

// ---------------------------------------------------------------------------
// Kernel 2: fused block-diagonal GRU.
// BM=256 x BN=64, BK=32, 512 thr = 8 waves (4m x 2n), wave tile 64x32
// (m_rep=2, mfma_f32_32x32x16_bf16). acc = 8 x f32x16 = 128 regs.
// Ring-4 LDS (128 KB), stage-ahead-3, uniform 4 gld_lds/wave/step,
// counted vmcnt(8). Grid 256 = 1 block/CU.
// ---------------------------------------------------------------------------
__global__ __launch_bounds__(512, 2) void gru_kernel(
    const float* __restrict__ hst,
    const short* __restrict__ Wcat, const short* __restrict__ Aimg,
    const float* __restrict__ b_ih, const float* __restrict__ b_hh,
    float* __restrict__ out)
{
    __shared__ short ldsA[4][8192];           // 4 x 16 KB  [row 0..255][64B swz]
    __shared__ short ldsB[4][8192];           // 4 x 16 KB  (12 KB real + 4 KB pad)

    const int tid = threadIdx.x;
    const int nblk = blockIdx.x & 7;          // XCD-local weight slice
    const int rr_ = blockIdx.x >> 3;          // 0..31
    const int bt = rr_ >> 3;                  // 0..3 batch tile (slow)
    const int jt = rr_ & 7;                   // 0..7 j tile (fast -> A L2 reuse)
    const int j0b = jt * 64;
    const int brow0 = bt * 256;

    const int lane = tid & 63;
    const int wave = tid >> 6;                // 0..7
    const int wm = wave >> 1;                 // 0..3 (64-row slice)
    const int wn = wave & 1;                  // 0..1 (32-col slice)
    const int l31 = lane & 31;
    const int k8 = lane >> 5;

    // B staging: 2 chunks/thread of padded 16 KB slot (1024 chunks)
    auto bsrc_of = [&](int c) -> size_t {     // c in [0,768) real
        const int g = c >> 8, j = (c & 255) >> 2, ci = c & 3;
        return ((size_t)nblk * 1536 + (size_t)g * 512 + (size_t)(j0b + j)) * 1024
             + (size_t)((ci ^ ((j >> 1) & 3)) * 8);
    };
    const size_t bsrc0 = bsrc_of(tid);                                   // c = tid
    const size_t bsrc1 = bsrc_of(tid < 256 ? tid + 512 : tid + 256);     // pad remap
    const size_t a_tile0 = ((size_t)(bt * 8 + nblk) * 32) << 14;         // bytes

    f32x16 acc_r[2] = {};
    f32x16 acc_z[2] = {};
    f32x16 acc_nx[2] = {};
    f32x16 acc_nh[2] = {};

    auto stage = [&](int buf, int ks) {
        const char* asrc = (const char*)Aimg + a_tile0 + ((size_t)ks << 14) + (size_t)tid * 16;
        char* adst = (char*)&ldsA[buf][0] + tid * 16;
        __builtin_amdgcn_global_load_lds(G1CAST(asrc), L3CAST(adst), 16, 0, 0);
        __builtin_amdgcn_global_load_lds(G1CAST(asrc + 8192), L3CAST(adst + 8192), 16, 0, 0);
        const short* ws = Wcat + (size_t)ks * 32;
        char* bdst = (char*)&ldsB[buf][0] + tid * 16;
        __builtin_amdgcn_global_load_lds(G1CAST(ws + bsrc0), L3CAST(bdst), 16, 0, 0);
        __builtin_amdgcn_global_load_lds(G1CAST(ws + bsrc1), L3CAST(bdst + 8192), 16, 0, 0);
    };

    const int jl = wn * 32 + l31;
    const int boff = jl * 64;
    const int bswz = ((jl >> 1) & 3) << 4;
    const int arow0 = wm * 64 + l31;
    const int arow1 = arow0 + 32;
    const int aoff0 = arow0 * 64;
    const int aoff1 = arow1 * 64;
    const int aswz0 = ((arow0 >> 1) & 3) << 4;
    const int aswz1 = ((arow1 >> 1) & 3) << 4;

    auto computeStep = [&](const short* Ab_s, const short* Bb_s, f32x16 (&accN)[2]) {
        const char* Ab = (const char*)Ab_s;
        const char* Bb = (const char*)Bb_s;
        #pragma unroll
        for (int ksub = 0; ksub < 2; ++ksub) {
            const int kb = ksub * 32 + k8 * 16;
            bf16x8 af0 = *(const bf16x8*)(Ab + aoff0 + (kb ^ aswz0));
            bf16x8 af1 = *(const bf16x8*)(Ab + aoff1 + (kb ^ aswz1));
            bf16x8 b0 = *(const bf16x8*)(Bb + 0 * 4096 + boff + (kb ^ bswz));
            bf16x8 b1 = *(const bf16x8*)(Bb + 1 * 4096 + boff + (kb ^ bswz));
            bf16x8 b2 = *(const bf16x8*)(Bb + 2 * 4096 + boff + (kb ^ bswz));
            acc_r[0] = __builtin_amdgcn_mfma_f32_32x32x16_bf16(af0, b0, acc_r[0], 0, 0, 0);
            acc_r[1] = __builtin_amdgcn_mfma_f32_32x32x16_bf16(af1, b0, acc_r[1], 0, 0, 0);
            acc_z[0] = __builtin_amdgcn_mfma_f32_32x32x16_bf16(af0, b1, acc_z[0], 0, 0, 0);
            acc_z[1] = __builtin_amdgcn_mfma_f32_32x32x16_bf16(af1, b1, acc_z[1], 0, 0, 0);
            accN[0]  = __builtin_amdgcn_mfma_f32_32x32x16_bf16(af0, b2, accN[0], 0, 0, 0);
            accN[1]  = __builtin_amdgcn_mfma_f32_32x32x16_bf16(af1, b2, accN[1], 0, 0, 0);
        }
    };

    // prologue: fill ring slots 0,1,2
    stage(0, 0); stage(1, 1); stage(2, 2);

    // main pipeline: wait stage(i), barrier, issue stage(i+3), compute(i)
    #pragma unroll 1
    for (int i = 0; i < 16; ++i) {
        asm volatile("s_waitcnt vmcnt(8)" ::: "memory");   // stage(i) landed
        __builtin_amdgcn_sched_barrier(0);
        __builtin_amdgcn_s_barrier();
        stage((i + 3) & 3, i + 3);
        computeStep(ldsA[i & 3], ldsB[i & 3], acc_nx);
    }
    #pragma unroll 1
    for (int i = 16; i < 29; ++i) {
        asm volatile("s_waitcnt vmcnt(8)" ::: "memory");
        __builtin_amdgcn_sched_barrier(0);
        __builtin_amdgcn_s_barrier();
        stage((i + 3) & 3, i + 3);
        computeStep(ldsA[i & 3], ldsB[i & 3], acc_nh);
    }
    // tail: i=29,30,31 (no stage left)
    asm volatile("s_waitcnt vmcnt(8)" ::: "memory");
    __builtin_amdgcn_sched_barrier(0);
    __builtin_amdgcn_s_barrier();
    computeStep(ldsA[29 & 3], ldsB[29 & 3], acc_nh);
    asm volatile("s_waitcnt vmcnt(4)" ::: "memory");
    __builtin_amdgcn_sched_barrier(0);
    __builtin_amdgcn_s_barrier();
    computeStep(ldsA[30 & 3], ldsB[30 & 3], acc_nh);
    asm volatile("s_waitcnt vmcnt(0)" ::: "memory");
    __builtin_amdgcn_sched_barrier(0);
    __builtin_amdgcn_s_barrier();
    computeStep(ldsA[31 & 3], ldsB[31 & 3], acc_nh);

    // ---- epilogue: gates + output (wave owns 64x32 tile) ----
    const int jb = j0b + wn * 32 + l31;       // [0,512)
    const int bb = nblk * 1536 + jb;
    const float br = b_ih[bb] + b_hh[bb];
    const float bz = b_ih[bb + 512] + b_hh[bb + 512];
    const float bnx = b_ih[bb + 1024];
    const float bnh = b_hh[bb + 1024];
    const int gcol = nblk * 512 + jb;
    #pragma unroll
    for (int m = 0; m < 2; ++m) {
        #pragma unroll
        for (int rr = 0; rr < 16; ++rr) {
            const int rowl = (rr & 3) + 8 * (rr >> 2) + 4 * k8;
            const int row = brow0 + wm * 64 + m * 32 + rowl;
            const size_t idx = (size_t)row * 4096 + gcol;
            const float sr = acc_r[m][rr] + br;
            const float sz = acc_z[m][rr] + bz;
            const float rg = 1.f / (1.f + __expf(-sr));
            const float zg = 1.f / (1.f + __expf(-sz));
            const float tin = (acc_nx[m][rr] + bnx) + rg * (acc_nh[m][rr] + bnh);
            const float e2 = __expf(-2.f * tin);
            const float ng = 2.f / (1.f + e2) - 1.f;
            const float hv = hst[idx];
            out[idx] = ng + zg * (hv - ng);
        }
    }
}

extern "C" void kernel_launch(void* const* d_in, const int* in_sizes, int n_in,
                              void* d_out, int out_size, void* d_ws, size_t ws_size,
                              hipStream_t stream) {
    (void)in_sizes; (void)n_in; (void)out_size; (void)ws_size;
    const float* x    = (const float*)d_in[0];
    const float* h    = (const float*)d_in[1];
    const float* W_ih = (const float*)d_in[2];
    const float* W_hh = (const float*)d_in[3];
    const float* b_ih = (const float*)d_in[4];
    const float* b_hh = (const float*)d_in[5];
    short* Wcat = (short*)d_ws;                              // 24 MB
    short* Aimg = (short*)d_ws + (size_t)12 * 1024 * 1024;   // 16 MB

    wconv_kernel<<<6144, 256, 0, stream>>>(W_ih, W_hh, Wcat);
    aconv_kernel<<<4096, 256, 0, stream>>>(x, h, Aimg);
    gru_kernel<<<256, 512, 0, stream>>>(h, Wcat, Aimg, b_ih, b_hh, (float*)d_out);
}

// Round 6
// 60.188 us; speedup vs baseline: 1.1622x; 1.1622x over previous
//
#include <hip/hip_runtime.h>
#include <hip/hip_bf16.h>
#include <stdint.h>

#define G1CAST(p) ((const __attribute__((address_space(1))) void*)(p))
#define L3CAST(p) ((__attribute__((address_space(3))) void*)(p))

typedef short bf16x8 __attribute__((ext_vector_type(8)));
typedef float f32x16 __attribute__((ext_vector_type(16)));

// 3-bit chunk swizzle for 128B rows: rows r and r' share a slot only when
// r' == r (mod 16) -> max 2-way LDS bank aliasing (free on CDNA4).
__device__ __host__ __forceinline__ int swz3(int r) {
    return (r & 7) ^ (((r >> 3) & 1) << 2);
}

static __device__ __forceinline__ short f2bf(float f) {
    __hip_bfloat16 b = __float2bfloat16(f);
    return __builtin_bit_cast(short, b);
}

// ---------------------------------------------------------------------------
// Kernel 1: relayout+convert weights to bf16 (linear image).
// W_cat[n][gate][j][kk], kk in [0,1024): kk<512 -> W_ih[n][gate*512+j][kk]
//                                        kk>=512 -> W_hh[n][gate*512+j][kk-512]
// ---------------------------------------------------------------------------
__global__ __launch_bounds__(256) void wconv_kernel(const float* __restrict__ Wih,
                                                    const float* __restrict__ Whh,
                                                    short* __restrict__ Wcat) {
    const int tid = blockIdx.x * 256 + threadIdx.x;
    const int64_t e = (int64_t)tid * 8;
    const int kk = (int)(e & 1023);
    const int row = (int)(e >> 10);
    const int n = row / 1536;
    const int gr = row - n * 1536;
    const float* src = (kk < 512)
        ? Wih + ((int64_t)n * 786432 + (int64_t)gr * 512 + kk)
        : Whh + ((int64_t)n * 786432 + (int64_t)gr * 512 + (kk - 512));
    const float4 a = ((const float4*)src)[0];
    const float4 b = ((const float4*)src)[1];
    bf16x8 o;
    o[0] = f2bf(a.x); o[1] = f2bf(a.y); o[2] = f2bf(a.z); o[3] = f2bf(a.w);
    o[4] = f2bf(b.x); o[5] = f2bf(b.y); o[6] = f2bf(b.z); o[7] = f2bf(b.w);
    *(bf16x8*)(Wcat + e) = o;
}

// ---------------------------------------------------------------------------
// Kernel 1b: convert x,h -> bf16 pre-swizzled LDS images.
// Image tile t=(bt*8+nblk)*16+ks is 16 KB: [r 0..127][8 chunks of 16B,
// chunk c stored at position c ^ swz3(r)]. ks<8 -> x k-slice, ks>=8 -> h.
// ---------------------------------------------------------------------------
__global__ __launch_bounds__(256) void aconv_kernel(const float* __restrict__ x,
                                                    const float* __restrict__ h,
                                                    short* __restrict__ Aimg) {
    const int gid = blockIdx.x * 256 + threadIdx.x;   // 1,048,576 threads
    const int c4 = gid & 7;                           // k-chunk (16B)
    const int r = (gid >> 3) & 127;                   // row in tile
    const int tile = gid >> 10;                       // 0..1023
    const int ks = tile & 15;
    const int nblk = (tile >> 4) & 7;
    const int bt = tile >> 7;                         // 0..7
    const float* base = (ks < 8) ? x : h;
    const float* src = base + ((size_t)(bt * 128 + r) * 4096
                               + nblk * 512 + (ks & 7) * 64 + c4 * 8);
    const float4 a = ((const float4*)src)[0];
    const float4 b = ((const float4*)src)[1];
    bf16x8 o;
    o[0] = f2bf(a.x); o[1] = f2bf(a.y); o[2] = f2bf(a.z); o[3] = f2bf(a.w);
    o[4] = f2bf(b.x); o[5] = f2bf(b.y); o[6] = f2bf(b.z); o[7] = f2bf(b.w);
    *(bf16x8*)(Aimg + (size_t)tile * 8192 + r * 64 + (c4 ^ swz3(r)) * 8) = o;
}

// ---------------------------------------------------------------------------
// Kernel 2: fused block-diagonal GRU.
// BM=128 x BN=64, BK=64 (128B rows, conflict-free swizzle), 256 thr =
// 4 waves (2m x 2n), wave tile 64x32 (m_rep=2, mfma_f32_32x32x16_bf16).
// acc = 8 x f32x16 = 128 regs. Double-buffered LDS (80 KB -> 2 blocks/CU),
// 2-phase schedule: vmcnt(0) -> barrier -> stage(i+1) -> compute(i).
// ---------------------------------------------------------------------------
__global__ __launch_bounds__(256, 2) void gru_kernel(
    const float* __restrict__ hst,
    const short* __restrict__ Wcat, const short* __restrict__ Aimg,
    const float* __restrict__ b_ih, const float* __restrict__ b_hh,
    float* __restrict__ out)
{
    __shared__ short ldsA[2][128 * 64];       // 2 x 16 KB  [r][128B swz row]
    __shared__ short ldsB[2][3 * 64 * 64];    // 2 x 24 KB  [g][j][128B swz row]

    const int tid = threadIdx.x;
    const int nblk = blockIdx.x & 7;          // XCD-local weight slice
    const int rr_ = blockIdx.x >> 3;          // 0..63
    const int bt = rr_ >> 3;                  // 0..7 batch tile (slow)
    const int jt = rr_ & 7;                   // 0..7 j tile (fast -> A L2 reuse)
    const int j0b = jt * 64;
    const int brow0 = bt * 128;

    const int lane = tid & 63;
    const int wave = tid >> 6;                // 0..3
    const int wm = wave >> 1;                 // 0..1 (64-row slice)
    const int wn = wave & 1;                  // 0..1 (32-col slice)
    const int l31 = lane & 31;
    const int k8 = lane >> 5;

    // ---- B staging source offsets (6 chunks/thread), bytes into Wcat ----
    // dest chunk q = tid + 256*u maps to [g][j][c]; source chunk = c ^ swz3(j)
    uint32_t bsrc[6];
    #pragma unroll
    for (int u = 0; u < 6; ++u) {
        const int q = tid + 256 * u;
        const int g = q >> 9;
        const int rem = q & 511;
        const int j = rem >> 3;
        const int c = rem & 7;
        bsrc[u] = (uint32_t)(((nblk * 1536 + g * 512 + j0b + j) * 1024
                              + (c ^ swz3(j)) * 8) * 2);   // bytes
    }
    const size_t a_tile0 = ((size_t)(bt * 8 + nblk) << 18);   // bytes (16 tiles x 16KB)

    f32x16 acc_r[2] = {};
    f32x16 acc_z[2] = {};
    f32x16 acc_nx[2] = {};
    f32x16 acc_nh[2] = {};

    auto stage = [&](int buf, int ks) {
        const char* as = (const char*)Aimg + a_tile0 + ((size_t)ks << 14) + (size_t)tid * 16;
        char* ad = (char*)&ldsA[buf][0] + tid * 16;
        #pragma unroll
        for (int u = 0; u < 4; ++u)
            __builtin_amdgcn_global_load_lds(G1CAST(as + u * 4096), L3CAST(ad + u * 4096), 16, 0, 0);
        const char* wsb = (const char*)Wcat + (size_t)ks * 128;   // k-offset in bytes
        char* bd = (char*)&ldsB[buf][0] + tid * 16;
        #pragma unroll
        for (int u = 0; u < 6; ++u)
            __builtin_amdgcn_global_load_lds(G1CAST(wsb + bsrc[u]), L3CAST(bd + u * 4096), 16, 0, 0);
    };

    // per-thread read offsets
    const int arow0 = wm * 64 + l31;
    const int arow1 = arow0 + 32;
    const int jrow = wn * 32 + l31;
    const int swA0 = swz3(arow0), swA1 = swz3(arow1), swB = swz3(jrow);
    const int abase0 = arow0 * 128, abase1 = arow1 * 128;
    const int bbase = jrow * 128;

    auto computeStep = [&](const short* Ab_s, const short* Bb_s, f32x16 (&accN)[2]) {
        const char* Ab = (const char*)Ab_s;
        const char* Bb = (const char*)Bb_s;
        #pragma unroll
        for (int ksub = 0; ksub < 4; ++ksub) {
            const int ch = ksub * 2 + k8;
            bf16x8 af0 = *(const bf16x8*)(Ab + abase0 + ((ch ^ swA0) << 4));
            bf16x8 af1 = *(const bf16x8*)(Ab + abase1 + ((ch ^ swA1) << 4));
            bf16x8 b0 = *(const bf16x8*)(Bb + 0 * 8192 + bbase + ((ch ^ swB) << 4));
            bf16x8 b1 = *(const bf16x8*)(Bb + 1 * 8192 + bbase + ((ch ^ swB) << 4));
            bf16x8 b2 = *(const bf16x8*)(Bb + 2 * 8192 + bbase + ((ch ^ swB) << 4));
            acc_r[0] = __builtin_amdgcn_mfma_f32_32x32x16_bf16(af0, b0, acc_r[0], 0, 0, 0);
            acc_r[1] = __builtin_amdgcn_mfma_f32_32x32x16_bf16(af1, b0, acc_r[1], 0, 0, 0);
            acc_z[0] = __builtin_amdgcn_mfma_f32_32x32x16_bf16(af0, b1, acc_z[0], 0, 0, 0);
            acc_z[1] = __builtin_amdgcn_mfma_f32_32x32x16_bf16(af1, b1, acc_z[1], 0, 0, 0);
            accN[0]  = __builtin_amdgcn_mfma_f32_32x32x16_bf16(af0, b2, accN[0], 0, 0, 0);
            accN[1]  = __builtin_amdgcn_mfma_f32_32x32x16_bf16(af1, b2, accN[1], 0, 0, 0);
        }
    };

    stage(0, 0);

    #pragma unroll 1
    for (int i = 0; i < 8; ++i) {
        asm volatile("s_waitcnt vmcnt(0)" ::: "memory");   // stage(i) landed
        __builtin_amdgcn_sched_barrier(0);
        __builtin_amdgcn_s_barrier();                      // readers of buf[(i+1)&1] done
        stage((i + 1) & 1, i + 1);                         // overlaps compute(i)
        computeStep(ldsA[i & 1], ldsB[i & 1], acc_nx);
    }
    #pragma unroll 1
    for (int i = 8; i < 16; ++i) {
        asm volatile("s_waitcnt vmcnt(0)" ::: "memory");
        __builtin_amdgcn_sched_barrier(0);
        __builtin_amdgcn_s_barrier();
        if (i < 15) stage((i + 1) & 1, i + 1);
        computeStep(ldsA[i & 1], ldsB[i & 1], acc_nh);
    }

    // ---- epilogue: gates + output (wave owns 64x32 tile) ----
    const int jb = j0b + wn * 32 + l31;       // [0,512)
    const int bb = nblk * 1536 + jb;
    const float br = b_ih[bb] + b_hh[bb];
    const float bz = b_ih[bb + 512] + b_hh[bb + 512];
    const float bnx = b_ih[bb + 1024];
    const float bnh = b_hh[bb + 1024];
    const int gcol = nblk * 512 + jb;
    #pragma unroll
    for (int m = 0; m < 2; ++m) {
        #pragma unroll
        for (int rr = 0; rr < 16; ++rr) {
            const int rowl = (rr & 3) + 8 * (rr >> 2) + 4 * k8;
            const int row = brow0 + wm * 64 + m * 32 + rowl;
            const size_t idx = (size_t)row * 4096 + gcol;
            const float sr = acc_r[m][rr] + br;
            const float sz = acc_z[m][rr] + bz;
            const float rg = 1.f / (1.f + __expf(-sr));
            const float zg = 1.f / (1.f + __expf(-sz));
            const float tin = (acc_nx[m][rr] + bnx) + rg * (acc_nh[m][rr] + bnh);
            const float e2 = __expf(-2.f * tin);
            const float ng = 2.f / (1.f + e2) - 1.f;
            const float hv = hst[idx];
            out[idx] = ng + zg * (hv - ng);
        }
    }
}

extern "C" void kernel_launch(void* const* d_in, const int* in_sizes, int n_in,
                              void* d_out, int out_size, void* d_ws, size_t ws_size,
                              hipStream_t stream) {
    (void)in_sizes; (void)n_in; (void)out_size; (void)ws_size;
    const float* x    = (const float*)d_in[0];
    const float* h    = (const float*)d_in[1];
    const float* W_ih = (const float*)d_in[2];
    const float* W_hh = (const float*)d_in[3];
    const float* b_ih = (const float*)d_in[4];
    const float* b_hh = (const float*)d_in[5];
    short* Wcat = (short*)d_ws;                              // 24 MB
    short* Aimg = (short*)d_ws + (size_t)12 * 1024 * 1024;   // 16 MB

    wconv_kernel<<<6144, 256, 0, stream>>>(W_ih, W_hh, Wcat);
    aconv_kernel<<<4096, 256, 0, stream>>>(x, h, Aimg);
    gru_kernel<<<512, 256, 0, stream>>>(h, Wcat, Aimg, b_ih, b_hh, (float*)d_out);
}